// Round 1
// baseline (211.562 us; speedup 1.0000x reference)
//
#include <hip/hip_runtime.h>

// RegistrationLoss: sim = -mean(NCC_9x9x9(warped, fixed)), reg = bending energy of flow,
// total = sim + 0.01*reg. Inputs f32: warped[2,1,128,128,128], fixed same, flow[2,3,128,128,128].
// Output: 3 floats [total, sim, reg].

#define DIM 128
#define V   4194304L      // 2*128^3  (B*C=2 voxels per image field)
#define NVOL6 12582912L   // 6*128^3  (flow elements)

__device__ __forceinline__ float wave_block_reduce_partial(float local, float* lds, int t, int nwaves) {
    // 64-lane butterfly then cross-wave via LDS; caller must have lds[nwaves]
    #pragma unroll
    for (int off = 32; off > 0; off >>= 1) local += __shfl_down(local, off, 64);
    if ((t & 63) == 0) lds[t >> 6] = local;
    __syncthreads();
    float s = 0.f;
    if (t == 0) {
        for (int i = 0; i < nwaves; ++i) s += lds[i];
    }
    return s; // valid on t==0 only
}

// ---------------- Pass 1: box-sum along W for 5 fields ----------------
// One block = one W-line (128 contiguous floats). Grid = 2*128*128 lines.
__global__ void pass1_w(const float* __restrict__ I, const float* __restrict__ J,
                        float* __restrict__ bufA) {
    __shared__ float li[DIM], lj[DIM];
    const int t = threadIdx.x;
    const long base = (long)blockIdx.x * DIM;
    const float iv = I[base + t];
    const float jv = J[base + t];
    li[t] = iv; lj[t] = jv;
    __syncthreads();
    float sI = 0.f, sJ = 0.f, sII = 0.f, sJJ = 0.f, sIJ = 0.f;
    #pragma unroll
    for (int k = -4; k <= 4; ++k) {
        const int idx = t + k;
        if (idx >= 0 && idx < DIM) {
            const float a = li[idx], b = lj[idx];
            sI += a; sJ += b; sII += a * a; sJJ += b * b; sIJ += a * b;
        }
    }
    const long g = base + t;
    bufA[g]         = sI;
    bufA[V + g]     = sJ;
    bufA[2L*V + g]  = sII;
    bufA[3L*V + g]  = sJJ;
    bufA[4L*V + g]  = sIJ;
}

// ---------------- Pass 2: box-sum along H (per-field) ----------------
// blockIdx.y = field, blockIdx.x enumerates (b*128+d)*8 + h-chunk (16 h per block).
__global__ void pass2_h(const float* __restrict__ bufA, float* __restrict__ bufB) {
    const int t = threadIdx.x;                 // w
    const int f = blockIdx.y;
    const int chunk = blockIdx.x;              // [0, 2048)
    const int bd = chunk >> 3;                 // b*128 + d
    const int h0 = (chunk & 7) << 4;
    const float* __restrict__ src = bufA + (long)f * V;
    float* __restrict__ dst       = bufB + (long)f * V;
    const long slab = (long)bd * (DIM * DIM);
    for (int h = h0; h < h0 + 16; ++h) {
        float s = 0.f;
        #pragma unroll
        for (int k = -4; k <= 4; ++k) {
            const int hh = h + k;
            if (hh >= 0 && hh < DIM) s += src[slab + hh * DIM + t];
        }
        dst[slab + h * DIM + t] = s;
    }
}

// ---------------- Pass 3: box-sum along D + NCC + block reduce ----------------
// blockIdx.x enumerates (b*128+h)*8 + d-chunk (16 d per block). Threads = w.
__global__ void pass3_d_ncc(const float* __restrict__ bufB, float* __restrict__ nccPartial) {
    const int t = threadIdx.x;                 // w
    const int chunk = blockIdx.x;              // [0, 2048)
    const int bh = chunk >> 3;                 // b*128 + h
    const int d0 = (chunk & 7) << 4;
    const int b = bh >> 7;
    const int h = bh & 127;
    const float inv_n = 1.0f / 729.0f;
    float local = 0.f;
    for (int d = d0; d < d0 + 16; ++d) {
        float sI = 0.f, sJ = 0.f, sII = 0.f, sJJ = 0.f, sIJ = 0.f;
        #pragma unroll
        for (int k = -4; k <= 4; ++k) {
            const int dd = d + k;
            if (dd >= 0 && dd < DIM) {
                const long idx = (((long)b * DIM + dd) * DIM + h) * DIM + t;
                sI  += bufB[idx];
                sJ  += bufB[V + idx];
                sII += bufB[2L*V + idx];
                sJJ += bufB[3L*V + idx];
                sIJ += bufB[4L*V + idx];
            }
        }
        const float ui = sI * inv_n, uj = sJ * inv_n;
        const float i2 = sII * inv_n - ui * ui;
        const float j2 = sJJ * inv_n - uj * uj;
        const float ij = sIJ * inv_n - ui * uj;
        local += ij * ij / (i2 * j2 + 1e-5f);
    }
    __shared__ float lds[2];
    const float s = wave_block_reduce_partial(local, lds, t, 2);
    if (t == 0) nccPartial[blockIdx.x] = s;
}

// ---------------- Bending energy ----------------
// Cross terms f_ij == f_ji as values; weight by count of valid (i,j) orderings.
__global__ void bending(const float* __restrict__ F, float* __restrict__ regPartial) {
    const float invS = 1.0f / 12386304.0f;   // 6*126*128*128  (i==j)
    const float invC = 1.0f / 12289536.0f;   // 6*127*126*128  (i!=j, symmetric)
    float local = 0.f;
    const long stride = (long)gridDim.x * blockDim.x;
    for (long q = (long)blockIdx.x * blockDim.x + threadIdx.x; q < NVOL6; q += stride) {
        const int r = (int)(q & 2097151);    // within one 128^3 volume
        const int d = r >> 14;
        const int h = (r >> 7) & 127;
        const int w = r & 127;
        const float f0 = F[q];
        const bool dm = d < 127, hm = h < 127, wm = w < 127;
        const bool dm2 = d < 126, hm2 = h < 126, wm2 = w < 126;
        const float fD = dm ? F[q + 16384] : 0.f;
        const float fH = hm ? F[q + 128]   : 0.f;
        const float fW = wm ? F[q + 1]     : 0.f;
        if (dm2) { const float x = F[q + 32768] - 2.f * fD + f0; local += x * x * invS; }
        if (hm2) { const float x = F[q + 256]   - 2.f * fH + f0; local += x * x * invS; }
        if (wm2) { const float x = F[q + 2]     - 2.f * fW + f0; local += x * x * invS; }
        if (dm && hm) {
            const float x = F[q + 16384 + 128] - fD - fH + f0;
            const float c = (dm2 ? 1.f : 0.f) + (hm2 ? 1.f : 0.f);
            local += x * x * invC * c;
        }
        if (dm && wm) {
            const float x = F[q + 16384 + 1] - fD - fW + f0;
            const float c = (dm2 ? 1.f : 0.f) + (wm2 ? 1.f : 0.f);
            local += x * x * invC * c;
        }
        if (hm && wm) {
            const float x = F[q + 128 + 1] - fH - fW + f0;
            const float c = (hm2 ? 1.f : 0.f) + (wm2 ? 1.f : 0.f);
            local += x * x * invC * c;
        }
    }
    __shared__ float lds[4];
    const float s = wave_block_reduce_partial(local, lds, threadIdx.x, 4);
    if (threadIdx.x == 0) regPartial[blockIdx.x] = s;
}

// ---------------- Finalize: deterministic fixed-order reduction ----------------
__global__ void finalize(const float* __restrict__ nccPartial, const float* __restrict__ regPartial,
                         float* __restrict__ out) {
    __shared__ float sdata[256];
    const int t = threadIdx.x;
    float a = 0.f;
    for (int i = t; i < 2048; i += 256) a += nccPartial[i];
    sdata[t] = a; __syncthreads();
    for (int s = 128; s > 0; s >>= 1) { if (t < s) sdata[t] += sdata[t + s]; __syncthreads(); }
    const float nccSum = sdata[0];
    __syncthreads();
    float b = 0.f;
    for (int i = t; i < 4096; i += 256) b += regPartial[i];
    sdata[t] = b; __syncthreads();
    for (int s = 128; s > 0; s >>= 1) { if (t < s) sdata[t] += sdata[t + s]; __syncthreads(); }
    if (t == 0) {
        const float reg = sdata[0];
        const float sim = -nccSum / (float)V;
        out[0] = sim + 0.01f * reg;   // total (SIM_W=1, REG_W=0.01)
        out[1] = sim;
        out[2] = reg;
    }
}

extern "C" void kernel_launch(void* const* d_in, const int* in_sizes, int n_in,
                              void* d_out, int out_size, void* d_ws, size_t ws_size,
                              hipStream_t stream) {
    const float* warped = (const float*)d_in[0];
    const float* fixedv = (const float*)d_in[1];
    const float* flow   = (const float*)d_in[2];
    float* out = (float*)d_out;
    float* ws  = (float*)d_ws;

    // ws layout (floats): [0,2048) nccPartial | [2048,6144) regPartial | pad |
    //                     [8192, 8192+5V) bufA | [.., +5V) bufB   (~168 MB total)
    float* nccPartial = ws;
    float* regPartial = ws + 2048;
    float* bufA = ws + 8192;
    float* bufB = bufA + 5L * V;

    pass1_w<<<dim3(32768), dim3(128), 0, stream>>>(warped, fixedv, bufA);
    pass2_h<<<dim3(2048, 5), dim3(128), 0, stream>>>(bufA, bufB);
    pass3_d_ncc<<<dim3(2048), dim3(128), 0, stream>>>(bufB, nccPartial);
    bending<<<dim3(4096), dim3(256), 0, stream>>>(flow, regPartial);
    finalize<<<dim3(1), dim3(256), 0, stream>>>(nccPartial, regPartial, out);
}

// Round 2
// 106.507 us; speedup vs baseline: 1.9864x; 1.9864x over previous
//
#include <hip/hip_runtime.h>

// RegistrationLoss: sim = -mean(NCC_9x9x9(warped, fixed)), reg = bending energy of flow,
// total = sim + 0.01*reg. Inputs f32: warped[2,1,128,128,128], fixed same, flow[2,3,128,128,128].
// Output: 3 floats [total, sim, reg].
//
// NCC pipeline (each element of each stream read exactly once from HBM):
//   ncc_wh: products + W-box (via 5 overlapping float2 loads, L1-served) + H-box
//           (register ring, thread marches h)  -> bufB[b][d][h][f][w]  (84 MB)
//   ncc_d:  D-box (register ring, thread marches d) + NCC + block reduce
// Bending energy: unchanged from round 1.

#define DIM 128
#define V   4194304L      // 2*128^3
#define NVOL6 12582912L   // 6*128^3

#define ZER2 make_float2(0.f, 0.f)

__device__ __forceinline__ float wave_block_reduce_partial(float local, float* lds, int t, int nwaves) {
    #pragma unroll
    for (int off = 32; off > 0; off >>= 1) local += __shfl_down(local, off, 64);
    if ((t & 63) == 0) lds[t >> 6] = local;
    __syncthreads();
    float s = 0.f;
    if (t == 0) {
        for (int i = 0; i < nwaves; ++i) s += lds[i];
    }
    return s; // valid on t==0 only
}

// ---------------- Kernel 1: products + W-box + H-box -> bufB ----------------
// Wave = (b, d, h-chunk of 16). Lane l owns w = 2l, 2l+1 (float2). Marches 24 h-steps,
// 9-deep register ring for the H window (statically indexed via full unroll).
__global__ __launch_bounds__(256) void ncc_wh(const float* __restrict__ I,
                                              const float* __restrict__ J,
                                              float* __restrict__ bufB) {
    const int lane = threadIdx.x & 63;
    const int wid  = (blockIdx.x << 2) + (threadIdx.x >> 6);
    const int e = wid & 7;            // h-chunk
    const int d = (wid >> 3) & 127;
    const int b = wid >> 10;
    const int h0 = e << 4;
    const int w0 = lane << 1;
    const int sliceBase = (b * 128 + d) * 16384;
    const bool vL2 = (lane >= 2), vL1 = (lane >= 1), vR1 = (lane <= 62), vR2 = (lane <= 61);

    float2 win[9][5];
    float2 hs[5];
    #pragma unroll
    for (int f = 0; f < 5; ++f) hs[f] = ZER2;

    #pragma unroll
    for (int s = 0; s < 24; ++s) {
        const int h_in = h0 - 4 + s;
        float2 iv[5], jv[5];          // W offsets -4,-2,0,+2,+4 (elements)
        if (h_in >= 0 && h_in < 128) {
            const float* rI = I + sliceBase + h_in * 128 + w0;
            const float* rJ = J + sliceBase + h_in * 128 + w0;
            iv[0] = vL2 ? *reinterpret_cast<const float2*>(rI - 4) : ZER2;
            iv[1] = vL1 ? *reinterpret_cast<const float2*>(rI - 2) : ZER2;
            iv[2] =       *reinterpret_cast<const float2*>(rI);
            iv[3] = vR1 ? *reinterpret_cast<const float2*>(rI + 2) : ZER2;
            iv[4] = vR2 ? *reinterpret_cast<const float2*>(rI + 4) : ZER2;
            jv[0] = vL2 ? *reinterpret_cast<const float2*>(rJ - 4) : ZER2;
            jv[1] = vL1 ? *reinterpret_cast<const float2*>(rJ - 2) : ZER2;
            jv[2] =       *reinterpret_cast<const float2*>(rJ);
            jv[3] = vR1 ? *reinterpret_cast<const float2*>(rJ + 2) : ZER2;
            jv[4] = vR2 ? *reinterpret_cast<const float2*>(rJ + 4) : ZER2;
        } else {
            #pragma unroll
            for (int o = 0; o < 5; ++o) { iv[o] = ZER2; jv[o] = ZER2; }
        }

        // 5 fields at each offset: i, j, i*i, j*j, i*j
        float2 v[5][5];
        #pragma unroll
        for (int o = 0; o < 5; ++o) {
            v[0][o] = iv[o];
            v[1][o] = jv[o];
            v[2][o] = make_float2(iv[o].x * iv[o].x, iv[o].y * iv[o].y);
            v[3][o] = make_float2(jv[o].x * jv[o].x, jv[o].y * jv[o].y);
            v[4][o] = make_float2(iv[o].x * jv[o].x, iv[o].y * jv[o].y);
        }

        #pragma unroll
        for (int f = 0; f < 5; ++f) {
            const float core = v[f][1].x + v[f][1].y + v[f][2].x + v[f][2].y
                             + v[f][3].x + v[f][3].y;
            float2 wb;
            wb.x = core + v[f][0].x + v[f][0].y + v[f][4].x;   // window w-4..w+4
            wb.y = core + v[f][0].y + v[f][4].x + v[f][4].y;   // window w-3..w+5
            if (s >= 9) { hs[f].x -= win[s % 9][f].x; hs[f].y -= win[s % 9][f].y; }
            hs[f].x += wb.x; hs[f].y += wb.y;
            win[s % 9][f] = wb;
        }

        if (s >= 8) {
            const int h_out = h0 + s - 8;
            float* o = bufB + ((b * 128 + d) * 128 + h_out) * 640 + w0;
            #pragma unroll
            for (int f = 0; f < 5; ++f)
                *reinterpret_cast<float2*>(o + f * 128) = hs[f];
        }
    }
}

// ---------------- Kernel 2: D-box + NCC + block reduce ----------------
// Block = (b, h), 512 threads: w = t&127, d-quarter = t>>7. Thread marches its 32-d
// quarter (+8 halo) with a 9x5 scalar register ring. bufB read exactly once.
__global__ __launch_bounds__(512) void ncc_d(const float* __restrict__ bufB,
                                             float* __restrict__ nccPartial) {
    const int t = threadIdx.x;
    const int w = t & 127;
    const int dq = t >> 7;            // 0..3
    const int b = blockIdx.x >> 7;
    const int h = blockIdx.x & 127;
    const int d0 = dq << 5;
    const float inv_n = 1.0f / 729.0f;

    float win[9][5];
    float rs[5] = {0.f, 0.f, 0.f, 0.f, 0.f};
    float local = 0.f;

    #pragma unroll
    for (int s = 0; s < 40; ++s) {
        const int dd = d0 - 4 + s;
        float x[5];
        if (dd >= 0 && dd < 128) {
            const float* p = bufB + ((b * 128 + dd) * 128 + h) * 640 + w;
            #pragma unroll
            for (int f = 0; f < 5; ++f) x[f] = p[f * 128];
        } else {
            #pragma unroll
            for (int f = 0; f < 5; ++f) x[f] = 0.f;
        }
        #pragma unroll
        for (int f = 0; f < 5; ++f) {
            if (s >= 9) rs[f] -= win[s % 9][f];
            rs[f] += x[f];
            win[s % 9][f] = x[f];
        }
        if (s >= 8) {
            const float ui = rs[0] * inv_n, uj = rs[1] * inv_n;
            const float i2 = rs[2] * inv_n - ui * ui;
            const float j2 = rs[3] * inv_n - uj * uj;
            const float ij = rs[4] * inv_n - ui * uj;
            local += ij * ij / (i2 * j2 + 1e-5f);
        }
    }

    __shared__ float lds[8];
    const float s = wave_block_reduce_partial(local, lds, t, 8);
    if (t == 0) nccPartial[blockIdx.x] = s;
}

// ---------------- Bending energy (unchanged) ----------------
__global__ void bending(const float* __restrict__ F, float* __restrict__ regPartial) {
    const float invS = 1.0f / 12386304.0f;   // 6*126*128*128  (i==j)
    const float invC = 1.0f / 12289536.0f;   // 6*127*126*128  (i!=j, symmetric)
    float local = 0.f;
    const long stride = (long)gridDim.x * blockDim.x;
    for (long q = (long)blockIdx.x * blockDim.x + threadIdx.x; q < NVOL6; q += stride) {
        const int r = (int)(q & 2097151);
        const int d = r >> 14;
        const int h = (r >> 7) & 127;
        const int w = r & 127;
        const float f0 = F[q];
        const bool dm = d < 127, hm = h < 127, wm = w < 127;
        const bool dm2 = d < 126, hm2 = h < 126, wm2 = w < 126;
        const float fD = dm ? F[q + 16384] : 0.f;
        const float fH = hm ? F[q + 128]   : 0.f;
        const float fW = wm ? F[q + 1]     : 0.f;
        if (dm2) { const float x = F[q + 32768] - 2.f * fD + f0; local += x * x * invS; }
        if (hm2) { const float x = F[q + 256]   - 2.f * fH + f0; local += x * x * invS; }
        if (wm2) { const float x = F[q + 2]     - 2.f * fW + f0; local += x * x * invS; }
        if (dm && hm) {
            const float x = F[q + 16384 + 128] - fD - fH + f0;
            const float c = (dm2 ? 1.f : 0.f) + (hm2 ? 1.f : 0.f);
            local += x * x * invC * c;
        }
        if (dm && wm) {
            const float x = F[q + 16384 + 1] - fD - fW + f0;
            const float c = (dm2 ? 1.f : 0.f) + (wm2 ? 1.f : 0.f);
            local += x * x * invC * c;
        }
        if (hm && wm) {
            const float x = F[q + 128 + 1] - fH - fW + f0;
            const float c = (hm2 ? 1.f : 0.f) + (wm2 ? 1.f : 0.f);
            local += x * x * invC * c;
        }
    }
    __shared__ float lds[4];
    const float s = wave_block_reduce_partial(local, lds, threadIdx.x, 4);
    if (threadIdx.x == 0) regPartial[blockIdx.x] = s;
}

// ---------------- Finalize ----------------
__global__ void finalize(const float* __restrict__ nccPartial, const float* __restrict__ regPartial,
                         float* __restrict__ out) {
    __shared__ float sdata[256];
    const int t = threadIdx.x;
    float a = 0.f;
    for (int i = t; i < 256; i += 256) a += nccPartial[i];
    sdata[t] = a; __syncthreads();
    for (int s = 128; s > 0; s >>= 1) { if (t < s) sdata[t] += sdata[t + s]; __syncthreads(); }
    const float nccSum = sdata[0];
    __syncthreads();
    float bsum = 0.f;
    for (int i = t; i < 4096; i += 256) bsum += regPartial[i];
    sdata[t] = bsum; __syncthreads();
    for (int s = 128; s > 0; s >>= 1) { if (t < s) sdata[t] += sdata[t + s]; __syncthreads(); }
    if (t == 0) {
        const float reg = sdata[0];
        const float sim = -nccSum / (float)V;
        out[0] = sim + 0.01f * reg;
        out[1] = sim;
        out[2] = reg;
    }
}

extern "C" void kernel_launch(void* const* d_in, const int* in_sizes, int n_in,
                              void* d_out, int out_size, void* d_ws, size_t ws_size,
                              hipStream_t stream) {
    const float* warped = (const float*)d_in[0];
    const float* fixedv = (const float*)d_in[1];
    const float* flow   = (const float*)d_in[2];
    float* out = (float*)d_out;
    float* ws  = (float*)d_ws;

    // ws layout (floats): [0,256) nccPartial | [256,4352) regPartial | pad |
    //                     [8192, 8192 + 2*128^3*... ) bufB (5 fields interleaved, ~84 MB)
    float* nccPartial = ws;
    float* regPartial = ws + 256;
    float* bufB = ws + 8192;

    // 2048 waves = 512 blocks x 4 waves; wave = (b, d, h-chunk)
    ncc_wh<<<dim3(512), dim3(256), 0, stream>>>(warped, fixedv, bufB);
    // 256 blocks = (b,h); 512 threads = 4 d-quarters x 128 w
    ncc_d<<<dim3(256), dim3(512), 0, stream>>>(bufB, nccPartial);
    bending<<<dim3(4096), dim3(256), 0, stream>>>(flow, regPartial);
    finalize<<<dim3(1), dim3(256), 0, stream>>>(nccPartial, regPartial, out);
}

// Round 3
// 82.055 us; speedup vs baseline: 2.5783x; 1.2980x over previous
//
#include <hip/hip_runtime.h>

// RegistrationLoss: sim = -mean(NCC_9x9x9(warped, fixed)), reg = bending energy of flow,
// total = sim + 0.01*reg. Inputs f32: warped[2,1,128,128,128], fixed same, flow[2,3,128,128,128].
// Output: 3 floats [total, sim, reg].

#define DIM 128
#define V   4194304L      // 2*128^3
#define NVOL6 12582912L   // 6*128^3

#define ZER2 make_float2(0.f, 0.f)

__device__ __forceinline__ float wave_block_reduce_partial(float local, float* lds, int t, int nwaves) {
    #pragma unroll
    for (int off = 32; off > 0; off >>= 1) local += __shfl_down(local, off, 64);
    if ((t & 63) == 0) lds[t >> 6] = local;
    __syncthreads();
    float s = 0.f;
    if (t == 0) {
        for (int i = 0; i < nwaves; ++i) s += lds[i];
    }
    return s; // valid on t==0 only
}

// ---------------- Kernel 1: products + W-box + H-box -> bufB ----------------
__global__ __launch_bounds__(256) void ncc_wh(const float* __restrict__ I,
                                              const float* __restrict__ J,
                                              float* __restrict__ bufB) {
    const int lane = threadIdx.x & 63;
    const int wid  = (blockIdx.x << 2) + (threadIdx.x >> 6);
    const int e = wid & 7;            // h-chunk
    const int d = (wid >> 3) & 127;
    const int b = wid >> 10;
    const int h0 = e << 4;
    const int w0 = lane << 1;
    const int sliceBase = (b * 128 + d) * 16384;
    const bool vL2 = (lane >= 2), vL1 = (lane >= 1), vR1 = (lane <= 62), vR2 = (lane <= 61);

    float2 win[9][5];
    float2 hs[5];
    #pragma unroll
    for (int f = 0; f < 5; ++f) hs[f] = ZER2;

    #pragma unroll
    for (int s = 0; s < 24; ++s) {
        const int h_in = h0 - 4 + s;
        float2 iv[5], jv[5];          // W offsets -4,-2,0,+2,+4 (elements)
        if (h_in >= 0 && h_in < 128) {
            const float* rI = I + sliceBase + h_in * 128 + w0;
            const float* rJ = J + sliceBase + h_in * 128 + w0;
            iv[0] = vL2 ? *reinterpret_cast<const float2*>(rI - 4) : ZER2;
            iv[1] = vL1 ? *reinterpret_cast<const float2*>(rI - 2) : ZER2;
            iv[2] =       *reinterpret_cast<const float2*>(rI);
            iv[3] = vR1 ? *reinterpret_cast<const float2*>(rI + 2) : ZER2;
            iv[4] = vR2 ? *reinterpret_cast<const float2*>(rI + 4) : ZER2;
            jv[0] = vL2 ? *reinterpret_cast<const float2*>(rJ - 4) : ZER2;
            jv[1] = vL1 ? *reinterpret_cast<const float2*>(rJ - 2) : ZER2;
            jv[2] =       *reinterpret_cast<const float2*>(rJ);
            jv[3] = vR1 ? *reinterpret_cast<const float2*>(rJ + 2) : ZER2;
            jv[4] = vR2 ? *reinterpret_cast<const float2*>(rJ + 4) : ZER2;
        } else {
            #pragma unroll
            for (int o = 0; o < 5; ++o) { iv[o] = ZER2; jv[o] = ZER2; }
        }

        float2 v[5][5];
        #pragma unroll
        for (int o = 0; o < 5; ++o) {
            v[0][o] = iv[o];
            v[1][o] = jv[o];
            v[2][o] = make_float2(iv[o].x * iv[o].x, iv[o].y * iv[o].y);
            v[3][o] = make_float2(jv[o].x * jv[o].x, jv[o].y * jv[o].y);
            v[4][o] = make_float2(iv[o].x * jv[o].x, iv[o].y * jv[o].y);
        }

        #pragma unroll
        for (int f = 0; f < 5; ++f) {
            const float core = v[f][1].x + v[f][1].y + v[f][2].x + v[f][2].y
                             + v[f][3].x + v[f][3].y;
            float2 wb;
            wb.x = core + v[f][0].x + v[f][0].y + v[f][4].x;
            wb.y = core + v[f][0].y + v[f][4].x + v[f][4].y;
            if (s >= 9) { hs[f].x -= win[s % 9][f].x; hs[f].y -= win[s % 9][f].y; }
            hs[f].x += wb.x; hs[f].y += wb.y;
            win[s % 9][f] = wb;
        }

        if (s >= 8) {
            const int h_out = h0 + s - 8;
            float* o = bufB + ((b * 128 + d) * 128 + h_out) * 640 + w0;
            #pragma unroll
            for (int f = 0; f < 5; ++f)
                *reinterpret_cast<float2*>(o + f * 128) = hs[f];
        }
    }
}

// ---------------- Kernel 2: D-box + NCC + block reduce ----------------
__global__ __launch_bounds__(512) void ncc_d(const float* __restrict__ bufB,
                                             float* __restrict__ nccPartial) {
    const int t = threadIdx.x;
    const int w = t & 127;
    const int dq = t >> 7;            // 0..3
    const int b = blockIdx.x >> 7;
    const int h = blockIdx.x & 127;
    const int d0 = dq << 5;
    const float inv_n = 1.0f / 729.0f;

    float win[9][5];
    float rs[5] = {0.f, 0.f, 0.f, 0.f, 0.f};
    float local = 0.f;

    #pragma unroll
    for (int s = 0; s < 40; ++s) {
        const int dd = d0 - 4 + s;
        float x[5];
        if (dd >= 0 && dd < 128) {
            const float* p = bufB + ((b * 128 + dd) * 128 + h) * 640 + w;
            #pragma unroll
            for (int f = 0; f < 5; ++f) x[f] = p[f * 128];
        } else {
            #pragma unroll
            for (int f = 0; f < 5; ++f) x[f] = 0.f;
        }
        #pragma unroll
        for (int f = 0; f < 5; ++f) {
            if (s >= 9) rs[f] -= win[s % 9][f];
            rs[f] += x[f];
            win[s % 9][f] = x[f];
        }
        if (s >= 8) {
            const float ui = rs[0] * inv_n, uj = rs[1] * inv_n;
            const float i2 = rs[2] * inv_n - ui * ui;
            const float j2 = rs[3] * inv_n - uj * uj;
            const float ij = rs[4] * inv_n - ui * uj;
            local += ij * ij / (i2 * j2 + 1e-5f);
        }
    }

    __shared__ float lds[8];
    const float s = wave_block_reduce_partial(local, lds, t, 8);
    if (t == 0) nccPartial[blockIdx.x] = s;
}

// ---------------- Bending energy: branch-free, float4-vectorized ----------------
// Thread owns 4 consecutive w. All loads unconditional with clamped offsets;
// validity enters as multiplicative 0/1/2 weights. ~9 independent loads/thread.
__global__ __launch_bounds__(256) void bending(const float* __restrict__ F,
                                               float* __restrict__ regPartial) {
    const float invS = 1.0f / 12386304.0f;   // 6*126*128*128  (i==j)
    const float invC = 1.0f / 12289536.0f;   // 6*127*126*128  (i!=j, both orderings)

    const int tid = blockIdx.x * 256 + threadIdx.x;     // [0, 3145728)
    const long e = (long)tid << 2;                       // element base (multiple of 4)
    const int r = (int)(e & 2097151);
    const int d = r >> 14;
    const int h = (r >> 7) & 127;
    const int w0 = r & 127;                              // 0,4,...,124

    const float* p = F + e;
    const int off4 = (w0 < 124) ? 4 : 0;                 // clamped w-tail offset
    const int oD  = (d < 127) ? 16384 : 0;
    const int oD2 = (d < 126) ? 32768 : 0;
    const int oH  = (h < 127) ? 128 : 0;
    const int oH2 = (h < 126) ? 256 : 0;

    const float4 a0  = *reinterpret_cast<const float4*>(p);
    const float2 s45 = *reinterpret_cast<const float2*>(p + off4);
    const float4 aD  = *reinterpret_cast<const float4*>(p + oD);
    const float  sD4 = (p + oD)[off4];
    const float4 aD2 = *reinterpret_cast<const float4*>(p + oD2);
    const float4 aH  = *reinterpret_cast<const float4*>(p + oH);
    const float  sH4 = (p + oH)[off4];
    const float4 aH2 = *reinterpret_cast<const float4*>(p + oH2);
    const float4 aDH = *reinterpret_cast<const float4*>(p + oD + oH);

    const float A0[6] = {a0.x, a0.y, a0.z, a0.w, s45.x, s45.y};
    const float AD[5] = {aD.x, aD.y, aD.z, aD.w, sD4};
    const float AH[5] = {aH.x, aH.y, aH.z, aH.w, sH4};
    const float AD2[4] = {aD2.x, aD2.y, aD2.z, aD2.w};
    const float AH2[4] = {aH2.x, aH2.y, aH2.z, aH2.w};
    const float ADH[4] = {aDH.x, aDH.y, aDH.z, aDH.w};

    const float mD2 = (d < 126) ? invS : 0.f;
    const float mH2 = (h < 126) ? invS : 0.f;
    const float cD  = (d < 126) ? 1.f : 0.f;
    const float cH  = (h < 126) ? 1.f : 0.f;
    const bool  vD  = d < 127, vH = h < 127;

    float local = 0.f;
    #pragma unroll
    for (int k = 0; k < 4; ++k) {
        const int wk = w0 + k;
        const float mW2 = (wk < 126) ? invS : 0.f;
        const float cW  = (wk < 126) ? 1.f : 0.f;
        const bool  vW  = wk < 127;

        const float xW = A0[k + 2] - 2.f * A0[k + 1] + A0[k];
        local += xW * xW * mW2;
        const float xD = AD2[k] - 2.f * AD[k] + A0[k];
        local += xD * xD * mD2;
        const float xH = AH2[k] - 2.f * AH[k] + A0[k];
        local += xH * xH * mH2;

        const float xDH = ADH[k] - AD[k] - AH[k] + A0[k];
        local += xDH * xDH * (((vD && vH) ? (cD + cH) : 0.f) * invC);
        const float xDW = AD[k + 1] - AD[k] - A0[k + 1] + A0[k];
        local += xDW * xDW * (((vD && vW) ? (cD + cW) : 0.f) * invC);
        const float xHW = AH[k + 1] - AH[k] - A0[k + 1] + A0[k];
        local += xHW * xHW * (((vH && vW) ? (cH + cW) : 0.f) * invC);
    }

    __shared__ float lds[4];
    const float s = wave_block_reduce_partial(local, lds, threadIdx.x, 4);
    if (threadIdx.x == 0) regPartial[blockIdx.x] = s;
}

// ---------------- Finalize ----------------
__global__ void finalize(const float* __restrict__ nccPartial, const float* __restrict__ regPartial,
                         float* __restrict__ out) {
    __shared__ float sdata[256];
    const int t = threadIdx.x;
    float a = 0.f;
    for (int i = t; i < 256; i += 256) a += nccPartial[i];
    sdata[t] = a; __syncthreads();
    for (int s = 128; s > 0; s >>= 1) { if (t < s) sdata[t] += sdata[t + s]; __syncthreads(); }
    const float nccSum = sdata[0];
    __syncthreads();
    float bsum = 0.f;
    for (int i = t; i < 12288; i += 256) bsum += regPartial[i];
    sdata[t] = bsum; __syncthreads();
    for (int s = 128; s > 0; s >>= 1) { if (t < s) sdata[t] += sdata[t + s]; __syncthreads(); }
    if (t == 0) {
        const float reg = sdata[0];
        const float sim = -nccSum / (float)V;
        out[0] = sim + 0.01f * reg;
        out[1] = sim;
        out[2] = reg;
    }
}

extern "C" void kernel_launch(void* const* d_in, const int* in_sizes, int n_in,
                              void* d_out, int out_size, void* d_ws, size_t ws_size,
                              hipStream_t stream) {
    const float* warped = (const float*)d_in[0];
    const float* fixedv = (const float*)d_in[1];
    const float* flow   = (const float*)d_in[2];
    float* out = (float*)d_out;
    float* ws  = (float*)d_ws;

    // ws layout (floats): [0,256) nccPartial | [256,12544) regPartial | pad |
    //                     [16384, ...) bufB (5 fields interleaved, ~84 MB)
    float* nccPartial = ws;
    float* regPartial = ws + 256;
    float* bufB = ws + 16384;

    ncc_wh<<<dim3(512), dim3(256), 0, stream>>>(warped, fixedv, bufB);
    ncc_d<<<dim3(256), dim3(512), 0, stream>>>(bufB, nccPartial);
    bending<<<dim3(12288), dim3(256), 0, stream>>>(flow, regPartial);
    finalize<<<dim3(1), dim3(256), 0, stream>>>(nccPartial, regPartial, out);
}